// Round 9
// baseline (70.031 us; speedup 1.0000x reference)
//
#include <hip/hip_runtime.h>

#define BATCH 16
#define NUM_HEADS 32
#define NUM_KV 8
#define GQ 4            // query heads per kv head
#define HD 128
#define PAGE 256        // cache block size
#define MAXB 8
#define NGROUP (BATCH * NUM_KV)   // 128 (b,kvh) groups
#define QSCALE 0.08838834764831845f

// ws layout: [int counter][pad to 512 B] then per (b,kvh,split):
//   [4 M][4 l][4*128 acc] = 520 floats
#define WS_STRIDE 520
#define PART_OFF 128    // float offset of partials (512 B)

template <int NSPLIT, int TPSZ>
__global__ __launch_bounds__(256) void pa_partial_steal(
    const float* __restrict__ q,
    const float* __restrict__ knew,
    const float* __restrict__ vnew,
    const float* __restrict__ kc,
    const float* __restrict__ vc,
    const int* __restrict__ block_tables,
    const int* __restrict__ context_lens,
    float* __restrict__ ws)
{
  constexpr int NITEM = NGROUP * NSPLIT;
  int* cnt = (int*)ws;
  float* part = ws + PART_OFF;

  int tid = threadIdx.x;
  int w = tid >> 6;       // wave 0..3
  int lane = tid & 63;
  int grp16 = lane >> 4;  // 16-lane token group
  int j = lane & 15;      // lane j owns dims [j*4,j*4+4) and [64+j*4,...)
  int tb = w * 4 + grp16; // token slot within one block iteration (16 tokens/iter)

  __shared__ float4 s_pv[TPSZ];       // scores then p, 4 heads packed per token
  __shared__ float s_redM[4][GQ];
  __shared__ float s_redL[4][GQ];
  __shared__ float s_acc[4][GQ][HD];
  __shared__ int s_item;

  for (;;) {
    if (tid == 0) s_item = atomicAdd(cnt, 1);
    __syncthreads();
    int item = s_item;
    if (item >= NITEM) return;

    // decode: kvh fastest, then b, then split (work front-loaded in queue order)
    int kvh = item & 7;
    int b = (item >> 3) & 15;
    int split = item >> 7;
    int ctx = context_lens[b];
    int start = split * TPSZ;
    if (start >= ctx) continue;        // cheap skip (uniform over block)
    int n = min(TPSZ, ctx - start);
    int page = block_tables[b * MAXB + (start >> 8)];
    int pbase = page * PAGE + (start & (PAGE - 1));

    // q fragments for the 4 query heads (L2/L1-hot after first item)
    float qr[GQ][8];
    #pragma unroll
    for (int g = 0; g < GQ; ++g) {
      const float* qp = q + ((size_t)(b * NUM_HEADS + kvh * GQ + g)) * HD;
      float4 a = *(const float4*)(qp + j * 4);
      float4 c = *(const float4*)(qp + 64 + j * 4);
      qr[g][0]=a.x*QSCALE; qr[g][1]=a.y*QSCALE; qr[g][2]=a.z*QSCALE; qr[g][3]=a.w*QSCALE;
      qr[g][4]=c.x*QSCALE; qr[g][5]=c.y*QSCALE; qr[g][6]=c.z*QSCALE; qr[g][7]=c.w*QSCALE;
    }

    const float* knew_row = knew + (size_t)(b * NUM_KV + kvh) * HD + j * 4;
    const float* vnew_row = vnew + (size_t)(b * NUM_KV + kvh) * HD + j * 4;
    size_t base_off = ((size_t)pbase * NUM_KV + kvh) * HD + j * 4;
    const float* kbase = kc + base_off;
    const float* vbase = vc + base_off;
    int newpos = ctx - 1 - start;      // in [0,n) iff this split holds the new token

    int iters = (n + 15) >> 4;

    // ---------- phase 1: all scores of the split ----------
    #pragma unroll 2
    for (int i = 0; i < iters; ++i) {
      int tl = tb + i * 16;
      int tlc = (tl < n) ? tl : 0;     // pad lanes re-read token 0 (L1 hit), masked later
      const float* krow = (tlc == newpos) ? knew_row
                                          : kbase + (size_t)tlc * (NUM_KV * HD);
      float4 k0 = *(const float4*)(krow);
      float4 k1 = *(const float4*)(krow + 64);
      float kk[8] = {k0.x,k0.y,k0.z,k0.w,k1.x,k1.y,k1.z,k1.w};
      float s0 = 0.f, s1 = 0.f, s2 = 0.f, s3 = 0.f;
      #pragma unroll
      for (int e = 0; e < 8; ++e) {
        s0 += qr[0][e] * kk[e];
        s1 += qr[1][e] * kk[e];
        s2 += qr[2][e] * kk[e];
        s3 += qr[3][e] * kk[e];
      }
      #pragma unroll
      for (int mask = 1; mask <= 8; mask <<= 1) {
        s0 += __shfl_xor(s0, mask);
        s1 += __shfl_xor(s1, mask);
        s2 += __shfl_xor(s2, mask);
        s3 += __shfl_xor(s3, mask);
      }
      if (j < 4) {
        float val = (j == 0) ? s0 : (j == 1) ? s1 : (j == 2) ? s2 : s3;
        ((float*)&s_pv[tl])[j] = val;  // garbage at tl>=n masked in phase 2
      }
    }
    __syncthreads();

    // ---------- phase 2: block-wide max, exp, sum over TPSZ tokens ----------
    constexpr int NWT = TPSZ / 64;     // waves holding tokens
    float Mg[GQ], Lg[GQ];
    {
      float4 sc;
      float sv0, sv1, sv2, sv3;
      if (tid < TPSZ) {
        sc = s_pv[tid];
        bool valid = tid < n;
        sv0 = valid ? sc.x : -1e30f;
        sv1 = valid ? sc.y : -1e30f;
        sv2 = valid ? sc.z : -1e30f;
        sv3 = valid ? sc.w : -1e30f;
        float m0 = sv0, m1 = sv1, m2 = sv2, m3 = sv3;
        #pragma unroll
        for (int mask = 1; mask <= 32; mask <<= 1) {
          m0 = fmaxf(m0, __shfl_xor(m0, mask));
          m1 = fmaxf(m1, __shfl_xor(m1, mask));
          m2 = fmaxf(m2, __shfl_xor(m2, mask));
          m3 = fmaxf(m3, __shfl_xor(m3, mask));
        }
        if (lane == 0) {
          s_redM[w][0] = m0; s_redM[w][1] = m1; s_redM[w][2] = m2; s_redM[w][3] = m3;
        }
      }
      __syncthreads();
      #pragma unroll
      for (int g = 0; g < GQ; ++g) {
        float mm = s_redM[0][g];
        #pragma unroll
        for (int ww = 1; ww < NWT; ++ww) mm = fmaxf(mm, s_redM[ww][g]);
        Mg[g] = mm;
      }
      if (tid < TPSZ) {
        float4 p4;
        p4.x = __expf(sv0 - Mg[0]);    // invalid t -> exp(-1e30-M) = 0
        p4.y = __expf(sv1 - Mg[1]);
        p4.z = __expf(sv2 - Mg[2]);
        p4.w = __expf(sv3 - Mg[3]);
        s_pv[tid] = p4;
        float l0 = p4.x, l1 = p4.y, l2 = p4.z, l3 = p4.w;
        #pragma unroll
        for (int mask = 1; mask <= 32; mask <<= 1) {
          l0 += __shfl_xor(l0, mask);
          l1 += __shfl_xor(l1, mask);
          l2 += __shfl_xor(l2, mask);
          l3 += __shfl_xor(l3, mask);
        }
        if (lane == 0) {
          s_redL[w][0] = l0; s_redL[w][1] = l1; s_redL[w][2] = l2; s_redL[w][3] = l3;
        }
      }
      __syncthreads();
      #pragma unroll
      for (int g = 0; g < GQ; ++g) {
        float ll = s_redL[0][g];
        #pragma unroll
        for (int ww = 1; ww < NWT; ++ww) ll += s_redL[ww][g];
        Lg[g] = ll;
      }
    }

    // ---------- phase 3: PV accumulate ----------
    float acc[GQ][8];
    #pragma unroll
    for (int g = 0; g < GQ; ++g)
      #pragma unroll
      for (int e = 0; e < 8; ++e) acc[g][e] = 0.f;

    #pragma unroll 2
    for (int i = 0; i < iters; ++i) {
      int tl = tb + i * 16;
      int tlc = (tl < n) ? tl : 0;
      const float* vrow = (tlc == newpos) ? vnew_row
                                          : vbase + (size_t)tlc * (NUM_KV * HD);
      float4 v0 = *(const float4*)(vrow);
      float4 v1 = *(const float4*)(vrow + 64);
      float vv[8] = {v0.x,v0.y,v0.z,v0.w,v1.x,v1.y,v1.z,v1.w};
      float4 pp = s_pv[tl];            // p == 0 for tl >= n
      #pragma unroll
      for (int e = 0; e < 8; ++e) {
        acc[0][e] += pp.x * vv[e];
        acc[1][e] += pp.y * vv[e];
        acc[2][e] += pp.z * vv[e];
        acc[3][e] += pp.w * vv[e];
      }
    }

    // ---------- phase 4: additive merge + partial write ----------
    #pragma unroll
    for (int g = 0; g < GQ; ++g)
      #pragma unroll
      for (int e = 0; e < 8; ++e) {
        acc[g][e] += __shfl_xor(acc[g][e], 16);
        acc[g][e] += __shfl_xor(acc[g][e], 32);
      }
    if (lane < 16) {
      #pragma unroll
      for (int g = 0; g < GQ; ++g) {
        #pragma unroll
        for (int e = 0; e < 4; ++e) s_acc[w][g][j * 4 + e] = acc[g][e];
        #pragma unroll
        for (int e = 4; e < 8; ++e) s_acc[w][g][64 + j * 4 + e - 4] = acc[g][e];
      }
    }
    __syncthreads();

    float* outp = part + (size_t)(((b * NUM_KV) + kvh) * NSPLIT + split) * WS_STRIDE;
    #pragma unroll
    for (int idx = tid; idx < GQ * HD; idx += 256) {
      int g = idx >> 7;
      int d = idx & 127;
      float A = s_acc[0][g][d] + s_acc[1][g][d] + s_acc[2][g][d] + s_acc[3][g][d];
      outp[8 + idx] = A;
      if (d == 0) {
        outp[g] = Mg[g];
        outp[GQ + g] = Lg[g];
      }
    }
    // next loop iteration's s_item write is ordered by the top-of-loop barrier;
    // s_pv of this item is dead after phase-4's __syncthreads.
  }
}

template <int NSPLIT, int TPSZ>
__global__ __launch_bounds__(128) void pa_reduce(
    const float* __restrict__ ws,
    const int* __restrict__ context_lens,
    float* __restrict__ out)
{
  const float* part = ws + PART_OFF;
  int blk = blockIdx.x;     // (b, kv, g)
  int g  = blk & 3;
  int kv = (blk >> 2) & 7;
  int b  = blk >> 5;
  int d  = threadIdx.x;
  int ctx = context_lens[b];
  int ns = (ctx + TPSZ - 1) / TPSZ;
  const float* base = part + (size_t)((b * NUM_KV + kv) * NSPLIT) * WS_STRIDE;

  float M = -1e30f;
  for (int s = 0; s < ns; ++s) M = fmaxf(M, base[s * WS_STRIDE + g]);
  float Lsum = 0.f, A = 0.f;
  for (int s = 0; s < ns; ++s) {
    float e = __expf(base[s * WS_STRIDE + g] - M);
    Lsum += base[s * WS_STRIDE + GQ + g] * e;
    A    += base[s * WS_STRIDE + 8 + g * HD + d] * e;
  }
  out[((size_t)(b * NUM_HEADS) + kv * GQ + g) * HD + d] = A / Lsum;
}

extern "C" void kernel_launch(void* const* d_in, const int* in_sizes, int n_in,
                              void* d_out, int out_size, void* d_ws, size_t ws_size,
                              hipStream_t stream) {
  const float* q  = (const float*)d_in[0];
  const float* k  = (const float*)d_in[1];
  const float* v  = (const float*)d_in[2];
  const float* kc = (const float*)d_in[3];
  const float* vc = (const float*)d_in[4];
  const int* block_tables = (const int*)d_in[5];
  const int* context_lens = (const int*)d_in[6];
  // d_in[7] = slot_mapping: not needed (new-token position derived from context_lens)

  float* ws = (float*)d_ws;
  float* out = (float*)d_out;

  // zero the work-queue counter (captured into the graph; re-runs every replay)
  hipMemsetAsync(d_ws, 0, 512, stream);

  size_t need16 = 512 + (size_t)NGROUP * 16 * WS_STRIDE * sizeof(float);
  if (ws_size >= need16) {
    pa_partial_steal<16, 128><<<1024, 256, 0, stream>>>(
        q, k, v, kc, vc, block_tables, context_lens, ws);
    pa_reduce<16, 128><<<BATCH * NUM_KV * GQ, 128, 0, stream>>>(ws, context_lens, out);
  } else {
    pa_partial_steal<8, 256><<<1024, 256, 0, stream>>>(
        q, k, v, kc, vc, block_tables, context_lens, ws);
    pa_reduce<8, 256><<<BATCH * NUM_KV * GQ, 128, 0, stream>>>(ws, context_lens, out);
  }
}

// Round 10
// 50.317 us; speedup vs baseline: 1.3918x; 1.3918x over previous
//
#include <hip/hip_runtime.h>

#define BATCH 16
#define NUM_HEADS 32
#define NUM_KV 8
#define GQ 4            // query heads per kv head
#define HD 128
#define PAGE 256        // cache block size
#define MAXB 8
#define NGROUP (BATCH * NUM_KV)   // 128 (b,kvh) groups
#define QSCALE 0.08838834764831845f

// ws layout per (b,kvh,split): [4 M][4 l][4*128 acc] = 520 floats
#define WS_STRIDE 520

template <int NSPLIT>
__global__ __launch_bounds__(256) void pa_partial(
    const float* __restrict__ q,
    const float* __restrict__ knew,
    const float* __restrict__ vnew,
    const float* __restrict__ kc,
    const float* __restrict__ vc,
    const int* __restrict__ block_tables,
    const int* __restrict__ context_lens,
    float* __restrict__ ws)
{
  constexpr int TPSZ = 2048 / NSPLIT;
  constexpr int NWT = (TPSZ + 63) / 64;   // waves holding tokens in phase 2

  int blk = blockIdx.x;
  int b, kvh, split;
  if constexpr (NSPLIT == 32) {
    // grid 4096, ~2048 resident -> hardware backfill balances data-dependent work.
    // Initial co-set {i+256k}: 8 distinct b, 8 distinct even splits. Bijective.
    int kv_ = blk & 7;
    int u = (blk >> 3) & 31;
    int t = (blk >> 8) & 7;
    int w2 = blk >> 11;                 // 0: even splits (first wave), 1: odd (backfill)
    kvh = kv_;
    b = ((u & 1) << 3) | t;
    split = ((((u >> 1) + (t << 1)) & 15) << 1) | w2;
  } else {
    // R8 stratified decode (NSPLIT == 8)
    int t = blk >> 8;
    int r = blk & 255;
    b = (t << 2) | (r & 3);
    kvh = (r >> 2) & 7;
    split = ((r >> 5) + (t << 1)) & 7;
  }

  int ctx = context_lens[b];
  int start = split * TPSZ;
  if (start >= ctx) return;            // uniform over block; vacates slot instantly
  int n = min(TPSZ, ctx - start);
  int page = block_tables[b * MAXB + (start >> 8)];
  int pbase = page * PAGE + (start & (PAGE - 1));

  int tid = threadIdx.x;
  int w = tid >> 6;       // wave 0..3
  int lane = tid & 63;
  int grp = lane >> 4;    // 16-lane token group
  int j = lane & 15;      // lane j owns dims [j*4,j*4+4) and [64+j*4,...)
  int tb = w * 4 + grp;   // token slot within one block iteration (16 tokens/iter)

  __shared__ float4 s_pv[TPSZ];       // scores then p, 4 heads packed per token
  __shared__ float s_redM[NWT][GQ];
  __shared__ float s_redL[NWT][GQ];
  __shared__ float s_acc[4][GQ][HD];

  // q for this kv head's 4 query heads, pre-scaled, in the lane's dim layout
  float qr[GQ][8];
  #pragma unroll
  for (int g = 0; g < GQ; ++g) {
    const float* qp = q + ((size_t)(b * NUM_HEADS + kvh * GQ + g)) * HD;
    float4 a = *(const float4*)(qp + j * 4);
    float4 c = *(const float4*)(qp + 64 + j * 4);
    qr[g][0]=a.x*QSCALE; qr[g][1]=a.y*QSCALE; qr[g][2]=a.z*QSCALE; qr[g][3]=a.w*QSCALE;
    qr[g][4]=c.x*QSCALE; qr[g][5]=c.y*QSCALE; qr[g][6]=c.z*QSCALE; qr[g][7]=c.w*QSCALE;
  }

  const float* knew_row = knew + (size_t)(b * NUM_KV + kvh) * HD + j * 4;
  const float* vnew_row = vnew + (size_t)(b * NUM_KV + kvh) * HD + j * 4;
  size_t base_off = ((size_t)pbase * NUM_KV + kvh) * HD + j * 4;
  const float* kbase = kc + base_off;
  const float* vbase = vc + base_off;
  int newpos = ctx - 1 - start;        // in [0,n) iff this split holds the new token

  int iters = (n + 15) >> 4;

  // ---------- phase 1: all scores of the split ----------
  #pragma unroll 2
  for (int i = 0; i < iters; ++i) {
    int tl = tb + i * 16;
    int tlc = (tl < n) ? tl : 0;       // pad lanes re-read token 0 (L1 hit), masked later
    const float* krow = (tlc == newpos) ? knew_row
                                        : kbase + (size_t)tlc * (NUM_KV * HD);
    float4 k0 = *(const float4*)(krow);
    float4 k1 = *(const float4*)(krow + 64);
    float kk[8] = {k0.x,k0.y,k0.z,k0.w,k1.x,k1.y,k1.z,k1.w};
    float s0 = 0.f, s1 = 0.f, s2 = 0.f, s3 = 0.f;
    #pragma unroll
    for (int e = 0; e < 8; ++e) {
      s0 += qr[0][e] * kk[e];
      s1 += qr[1][e] * kk[e];
      s2 += qr[2][e] * kk[e];
      s3 += qr[3][e] * kk[e];
    }
    #pragma unroll
    for (int mask = 1; mask <= 8; mask <<= 1) {
      s0 += __shfl_xor(s0, mask);
      s1 += __shfl_xor(s1, mask);
      s2 += __shfl_xor(s2, mask);
      s3 += __shfl_xor(s3, mask);
    }
    if (j < 4) {
      float val = (j == 0) ? s0 : (j == 1) ? s1 : (j == 2) ? s2 : s3;
      ((float*)&s_pv[tl])[j] = val;    // garbage at tl>=n masked in phase 2
    }
  }
  __syncthreads();

  // ---------- phase 2: block-wide max, exp, sum (token t = tid) ----------
  float Mg[GQ], Lg[GQ];
  {
    float sv0, sv1, sv2, sv3;
    if (tid < TPSZ) {
      float4 sc = s_pv[tid];
      bool valid = tid < n;
      sv0 = valid ? sc.x : -1e30f;
      sv1 = valid ? sc.y : -1e30f;
      sv2 = valid ? sc.z : -1e30f;
      sv3 = valid ? sc.w : -1e30f;
      float m0 = sv0, m1 = sv1, m2 = sv2, m3 = sv3;
      #pragma unroll
      for (int mask = 1; mask <= 32; mask <<= 1) {
        m0 = fmaxf(m0, __shfl_xor(m0, mask));
        m1 = fmaxf(m1, __shfl_xor(m1, mask));
        m2 = fmaxf(m2, __shfl_xor(m2, mask));
        m3 = fmaxf(m3, __shfl_xor(m3, mask));
      }
      if (lane == 0) {
        s_redM[w][0] = m0; s_redM[w][1] = m1; s_redM[w][2] = m2; s_redM[w][3] = m3;
      }
    }
    __syncthreads();
    #pragma unroll
    for (int g = 0; g < GQ; ++g) {
      float mm = s_redM[0][g];
      #pragma unroll
      for (int ww = 1; ww < NWT; ++ww) mm = fmaxf(mm, s_redM[ww][g]);
      Mg[g] = mm;
    }
    if (tid < TPSZ) {
      float4 p4;
      p4.x = __expf(sv0 - Mg[0]);      // invalid t -> exp(-1e30-M) = 0
      p4.y = __expf(sv1 - Mg[1]);
      p4.z = __expf(sv2 - Mg[2]);
      p4.w = __expf(sv3 - Mg[3]);
      s_pv[tid] = p4;
      float l0 = p4.x, l1 = p4.y, l2 = p4.z, l3 = p4.w;
      #pragma unroll
      for (int mask = 1; mask <= 32; mask <<= 1) {
        l0 += __shfl_xor(l0, mask);
        l1 += __shfl_xor(l1, mask);
        l2 += __shfl_xor(l2, mask);
        l3 += __shfl_xor(l3, mask);
      }
      if (lane == 0) {
        s_redL[w][0] = l0; s_redL[w][1] = l1; s_redL[w][2] = l2; s_redL[w][3] = l3;
      }
    }
    __syncthreads();
    #pragma unroll
    for (int g = 0; g < GQ; ++g) {
      float ll = s_redL[0][g];
      #pragma unroll
      for (int ww = 1; ww < NWT; ++ww) ll += s_redL[ww][g];
      Lg[g] = ll;
    }
  }

  // ---------- phase 3: PV accumulate ----------
  float acc[GQ][8];
  #pragma unroll
  for (int g = 0; g < GQ; ++g)
    #pragma unroll
    for (int e = 0; e < 8; ++e) acc[g][e] = 0.f;

  #pragma unroll 2
  for (int i = 0; i < iters; ++i) {
    int tl = tb + i * 16;
    int tlc = (tl < n) ? tl : 0;
    const float* vrow = (tlc == newpos) ? vnew_row
                                        : vbase + (size_t)tlc * (NUM_KV * HD);
    float4 v0 = *(const float4*)(vrow);
    float4 v1 = *(const float4*)(vrow + 64);
    float vv[8] = {v0.x,v0.y,v0.z,v0.w,v1.x,v1.y,v1.z,v1.w};
    float4 pp = s_pv[tl];              // p == 0 for tl >= n
    #pragma unroll
    for (int e = 0; e < 8; ++e) {
      acc[0][e] += pp.x * vv[e];
      acc[1][e] += pp.y * vv[e];
      acc[2][e] += pp.z * vv[e];
      acc[3][e] += pp.w * vv[e];
    }
  }

  // ---------- phase 4: additive merge across the 16 token-groups ----------
  #pragma unroll
  for (int g = 0; g < GQ; ++g)
    #pragma unroll
    for (int e = 0; e < 8; ++e) {
      acc[g][e] += __shfl_xor(acc[g][e], 16);
      acc[g][e] += __shfl_xor(acc[g][e], 32);
    }
  if (lane < 16) {
    #pragma unroll
    for (int g = 0; g < GQ; ++g) {
      #pragma unroll
      for (int e = 0; e < 4; ++e) s_acc[w][g][j * 4 + e] = acc[g][e];
      #pragma unroll
      for (int e = 4; e < 8; ++e) s_acc[w][g][64 + j * 4 + e - 4] = acc[g][e];
    }
  }
  __syncthreads();

  float* outp = ws + (size_t)(((b * NUM_KV) + kvh) * NSPLIT + split) * WS_STRIDE;
  #pragma unroll
  for (int idx = tid; idx < GQ * HD; idx += 256) {
    int g = idx >> 7;
    int d = idx & 127;
    float A = s_acc[0][g][d] + s_acc[1][g][d] + s_acc[2][g][d] + s_acc[3][g][d];
    outp[8 + idx] = A;
    if (d == 0) {
      outp[g] = Mg[g];
      outp[GQ + g] = Lg[g];
    }
  }
}

template <int NSPLIT>
__global__ __launch_bounds__(128) void pa_reduce(
    const float* __restrict__ ws,
    const int* __restrict__ context_lens,
    float* __restrict__ out)
{
  constexpr int TPSZ = 2048 / NSPLIT;
  int blk = blockIdx.x;     // (b, kv, g)
  int g  = blk & 3;
  int kv = (blk >> 2) & 7;
  int b  = blk >> 5;
  int d  = threadIdx.x;
  int ctx = context_lens[b];
  int ns = (ctx + TPSZ - 1) / TPSZ;
  const float* base = ws + (size_t)((b * NUM_KV + kv) * NSPLIT) * WS_STRIDE;

  float M = -1e30f;
  for (int s = 0; s < ns; ++s) M = fmaxf(M, base[s * WS_STRIDE + g]);
  float Lsum = 0.f, A = 0.f;
  for (int s = 0; s < ns; ++s) {
    float e = __expf(base[s * WS_STRIDE + g] - M);
    Lsum += base[s * WS_STRIDE + GQ + g] * e;
    A    += base[s * WS_STRIDE + 8 + g * HD + d] * e;
  }
  out[((size_t)(b * NUM_HEADS) + kv * GQ + g) * HD + d] = A / Lsum;
}

extern "C" void kernel_launch(void* const* d_in, const int* in_sizes, int n_in,
                              void* d_out, int out_size, void* d_ws, size_t ws_size,
                              hipStream_t stream) {
  const float* q  = (const float*)d_in[0];
  const float* k  = (const float*)d_in[1];
  const float* v  = (const float*)d_in[2];
  const float* kc = (const float*)d_in[3];
  const float* vc = (const float*)d_in[4];
  const int* block_tables = (const int*)d_in[5];
  const int* context_lens = (const int*)d_in[6];
  // d_in[7] = slot_mapping: not needed (new-token position derived from context_lens)

  float* ws = (float*)d_ws;
  float* out = (float*)d_out;

  size_t need32 = (size_t)NGROUP * 32 * WS_STRIDE * sizeof(float);
  if (ws_size >= need32) {
    pa_partial<32><<<NGROUP * 32, 256, 0, stream>>>(
        q, k, v, kc, vc, block_tables, context_lens, ws);
    pa_reduce<32><<<BATCH * NUM_KV * GQ, 128, 0, stream>>>(ws, context_lens, out);
  } else {
    pa_partial<8><<<NGROUP * 8, 256, 0, stream>>>(
        q, k, v, kc, vc, block_tables, context_lens, ws);
    pa_reduce<8><<<BATCH * NUM_KV * GQ, 128, 0, stream>>>(ws, context_lens, out);
  }
}

// Round 11
// 40.404 us; speedup vs baseline: 1.7333x; 1.2453x over previous
//
#include <hip/hip_runtime.h>

#define BATCH 16
#define NUM_HEADS 32
#define NUM_KV 8
#define GQ 4            // query heads per kv head
#define HD 128
#define PAGE 256        // cache block size
#define MAXB 8
#define NGROUP (BATCH * NUM_KV)   // 128 (b,kvh) groups
#define QSCALE 0.08838834764831845f

// ws layout per (b,kvh): SLOTS pieces of [4 M][4 l][4*128 acc] = 520 floats
#define WS_STRIDE 520
#define GRID 1280

// Uniform device-side balanced partition:
//   P  = clamp(ceil(8*total/NT), MINP, 256) target tokens/piece
//   nb = min(ceil(ctx/P), SLOTS) pieces per (b,kvh); size sz = ceil(ctx/nb) <= 256
template <int SLOTS, int NT, int MINP>
__device__ __forceinline__ int calc_P(const int* cx, int& total) {
  total = 0;
  #pragma unroll
  for (int bb = 0; bb < BATCH; ++bb) total += cx[bb];
  int P = (total * NUM_KV + NT - 1) / NT;
  if (P < MINP) P = MINP;
  if (P > 256) P = 256;
  return P;
}

template <int SLOTS, int NT, int MINP>
__global__ __launch_bounds__(256) void pa_partial(
    const float* __restrict__ q,
    const float* __restrict__ knew,
    const float* __restrict__ vnew,
    const float* __restrict__ kc,
    const float* __restrict__ vc,
    const int* __restrict__ block_tables,
    const int* __restrict__ context_lens,
    float* __restrict__ ws)
{
  int cx[BATCH];
  #pragma unroll
  for (int bb = 0; bb < BATCH; ++bb) cx[bb] = context_lens[bb];
  int total;
  int P = calc_P<SLOTS, NT, MINP>(cx, total);

  // decode: find (b, kvh, piece) for this block id under the balanced partition
  int blk = blockIdx.x;
  int b = -1, local = 0, acc_ = 0;
  #pragma unroll
  for (int bb = 0; bb < BATCH; ++bb) {
    int nb = (cx[bb] + P - 1) / P; if (nb > SLOTS) nb = SLOTS;
    int np = nb * NUM_KV;
    if (b < 0 && blk < acc_ + np) { b = bb; local = blk - acc_; }
    acc_ += np;
  }
  if (b < 0) return;                   // beyond total pieces (uniform)
  int ctx = cx[b];
  int nb = (ctx + P - 1) / P; if (nb > SLOTS) nb = SLOTS;
  int sz = (ctx + nb - 1) / nb;        // piece size <= 256
  int kvh = local & 7;
  int piece = local >> 3;
  int start = piece * sz;
  int n = min(sz, ctx - start);        // last piece may be short; always >= 1

  // a piece (<=256 tokens) touches at most 2 pages: preload both ids
  int pg0 = block_tables[b * MAXB + (start >> 8)];
  int pg1 = block_tables[b * MAXB + ((start + n - 1) >> 8)];
  int seg0 = start >> 8;

  int tid = threadIdx.x;
  int w = tid >> 6;       // wave 0..3
  int lane = tid & 63;
  int grp = lane >> 4;    // 16-lane token group
  int j = lane & 15;      // lane j owns dims [j*4,j*4+4) and [64+j*4,...)
  int tb = w * 4 + grp;   // token slot within one block iteration (16 tokens/iter)

  __shared__ float4 s_pv[256];        // scores then p, 4 heads packed per token
  __shared__ float s_redM[4][GQ];
  __shared__ float s_redL[4][GQ];
  __shared__ float s_acc[4][GQ][HD];

  // q for this kv head's 4 query heads, pre-scaled, in the lane's dim layout
  float qr[GQ][8];
  #pragma unroll
  for (int g = 0; g < GQ; ++g) {
    const float* qp = q + ((size_t)(b * NUM_HEADS + kvh * GQ + g)) * HD;
    float4 a = *(const float4*)(qp + j * 4);
    float4 c = *(const float4*)(qp + 64 + j * 4);
    qr[g][0]=a.x*QSCALE; qr[g][1]=a.y*QSCALE; qr[g][2]=a.z*QSCALE; qr[g][3]=a.w*QSCALE;
    qr[g][4]=c.x*QSCALE; qr[g][5]=c.y*QSCALE; qr[g][6]=c.z*QSCALE; qr[g][7]=c.w*QSCALE;
  }

  const float* knew_row = knew + (size_t)(b * NUM_KV + kvh) * HD + j * 4;
  const float* vnew_row = vnew + (size_t)(b * NUM_KV + kvh) * HD + j * 4;
  size_t lane_off = (size_t)kvh * HD + j * 4;
  int newpos = ctx - 1 - start;        // piece-local index of the new token (may be out of range)

  int iters = (n + 15) >> 4;

  // ---------- phase 1: all scores of the piece ----------
  #pragma unroll 2
  for (int i = 0; i < iters; ++i) {
    int tl = tb + i * 16;
    int tlc = (tl < n) ? tl : 0;       // pad lanes re-read token 0 (L1 hit), masked later
    int tok = start + tlc;
    int pg = ((tok >> 8) == seg0) ? pg0 : pg1;
    int row = pg * PAGE + (tok & 255);
    const float* krow = (tlc == newpos) ? knew_row
                                        : kc + (size_t)row * (NUM_KV * HD) + lane_off;
    float4 k0 = *(const float4*)(krow);
    float4 k1 = *(const float4*)(krow + 64);
    float kk[8] = {k0.x,k0.y,k0.z,k0.w,k1.x,k1.y,k1.z,k1.w};
    float s0 = 0.f, s1 = 0.f, s2 = 0.f, s3 = 0.f;
    #pragma unroll
    for (int e = 0; e < 8; ++e) {
      s0 += qr[0][e] * kk[e];
      s1 += qr[1][e] * kk[e];
      s2 += qr[2][e] * kk[e];
      s3 += qr[3][e] * kk[e];
    }
    #pragma unroll
    for (int mask = 1; mask <= 8; mask <<= 1) {
      s0 += __shfl_xor(s0, mask);
      s1 += __shfl_xor(s1, mask);
      s2 += __shfl_xor(s2, mask);
      s3 += __shfl_xor(s3, mask);
    }
    if (j < 4) {
      float val = (j == 0) ? s0 : (j == 1) ? s1 : (j == 2) ? s2 : s3;
      ((float*)&s_pv[tl])[j] = val;    // garbage at tl>=n masked in phase 2
    }
  }
  __syncthreads();

  // ---------- phase 2: block-wide max, exp, sum (token t = tid) ----------
  float4 sc = s_pv[tid];
  bool valid = tid < n;
  float sv0 = valid ? sc.x : -1e30f;   // select (not fmax): NaN-safe for junk LDS
  float sv1 = valid ? sc.y : -1e30f;
  float sv2 = valid ? sc.z : -1e30f;
  float sv3 = valid ? sc.w : -1e30f;
  float m0 = sv0, m1 = sv1, m2 = sv2, m3 = sv3;
  #pragma unroll
  for (int mask = 1; mask <= 32; mask <<= 1) {
    m0 = fmaxf(m0, __shfl_xor(m0, mask));
    m1 = fmaxf(m1, __shfl_xor(m1, mask));
    m2 = fmaxf(m2, __shfl_xor(m2, mask));
    m3 = fmaxf(m3, __shfl_xor(m3, mask));
  }
  if (lane == 0) {
    s_redM[w][0] = m0; s_redM[w][1] = m1; s_redM[w][2] = m2; s_redM[w][3] = m3;
  }
  __syncthreads();
  float Mg[GQ];
  #pragma unroll
  for (int g = 0; g < GQ; ++g)
    Mg[g] = fmaxf(fmaxf(s_redM[0][g], s_redM[1][g]), fmaxf(s_redM[2][g], s_redM[3][g]));
  float4 p4;
  p4.x = __expf(sv0 - Mg[0]);          // invalid t -> exp(-1e30-M) = 0
  p4.y = __expf(sv1 - Mg[1]);
  p4.z = __expf(sv2 - Mg[2]);
  p4.w = __expf(sv3 - Mg[3]);
  s_pv[tid] = p4;
  float l0 = p4.x, l1 = p4.y, l2 = p4.z, l3 = p4.w;
  #pragma unroll
  for (int mask = 1; mask <= 32; mask <<= 1) {
    l0 += __shfl_xor(l0, mask);
    l1 += __shfl_xor(l1, mask);
    l2 += __shfl_xor(l2, mask);
    l3 += __shfl_xor(l3, mask);
  }
  if (lane == 0) {
    s_redL[w][0] = l0; s_redL[w][1] = l1; s_redL[w][2] = l2; s_redL[w][3] = l3;
  }
  __syncthreads();
  float Lg[GQ];
  #pragma unroll
  for (int g = 0; g < GQ; ++g)
    Lg[g] = s_redL[0][g] + s_redL[1][g] + s_redL[2][g] + s_redL[3][g];

  // ---------- phase 3: PV accumulate ----------
  float acc[GQ][8];
  #pragma unroll
  for (int g = 0; g < GQ; ++g)
    #pragma unroll
    for (int e = 0; e < 8; ++e) acc[g][e] = 0.f;

  #pragma unroll 2
  for (int i = 0; i < iters; ++i) {
    int tl = tb + i * 16;
    int tlc = (tl < n) ? tl : 0;
    int tok = start + tlc;
    int pg = ((tok >> 8) == seg0) ? pg0 : pg1;
    int row = pg * PAGE + (tok & 255);
    const float* vrow = (tlc == newpos) ? vnew_row
                                        : vc + (size_t)row * (NUM_KV * HD) + lane_off;
    float4 v0 = *(const float4*)(vrow);
    float4 v1 = *(const float4*)(vrow + 64);
    float vv[8] = {v0.x,v0.y,v0.z,v0.w,v1.x,v1.y,v1.z,v1.w};
    float4 pp = s_pv[tl];              // p == 0 for tl >= n
    #pragma unroll
    for (int e = 0; e < 8; ++e) {
      acc[0][e] += pp.x * vv[e];
      acc[1][e] += pp.y * vv[e];
      acc[2][e] += pp.z * vv[e];
      acc[3][e] += pp.w * vv[e];
    }
  }

  // ---------- phase 4: additive merge across the 16 token-groups ----------
  #pragma unroll
  for (int g = 0; g < GQ; ++g)
    #pragma unroll
    for (int e = 0; e < 8; ++e) {
      acc[g][e] += __shfl_xor(acc[g][e], 16);
      acc[g][e] += __shfl_xor(acc[g][e], 32);
    }
  if (lane < 16) {
    #pragma unroll
    for (int g = 0; g < GQ; ++g) {
      #pragma unroll
      for (int e = 0; e < 4; ++e) s_acc[w][g][j * 4 + e] = acc[g][e];
      #pragma unroll
      for (int e = 4; e < 8; ++e) s_acc[w][g][64 + j * 4 + e - 4] = acc[g][e];
    }
  }
  __syncthreads();

  float* outp = ws + (size_t)(((b * NUM_KV) + kvh) * SLOTS + piece) * WS_STRIDE;
  #pragma unroll
  for (int idx = tid; idx < GQ * HD; idx += 256) {
    int g = idx >> 7;
    int d = idx & 127;
    float A = s_acc[0][g][d] + s_acc[1][g][d] + s_acc[2][g][d] + s_acc[3][g][d];
    outp[8 + idx] = A;
    if (d == 0) {
      outp[g] = Mg[g];
      outp[GQ + g] = Lg[g];
    }
  }
}

template <int SLOTS, int NT, int MINP>
__global__ __launch_bounds__(128) void pa_reduce(
    const float* __restrict__ ws,
    const int* __restrict__ context_lens,
    float* __restrict__ out)
{
  int cx[BATCH];
  #pragma unroll
  for (int bb = 0; bb < BATCH; ++bb) cx[bb] = context_lens[bb];
  int total;
  int P = calc_P<SLOTS, NT, MINP>(cx, total);

  int blk = blockIdx.x;     // (b, kv, g)
  int g  = blk & 3;
  int kv = (blk >> 2) & 7;
  int b  = blk >> 5;
  int d  = threadIdx.x;
  int ctx = cx[b];
  int nb = (ctx + P - 1) / P; if (nb > SLOTS) nb = SLOTS;
  const float* base = ws + (size_t)((b * NUM_KV + kv) * SLOTS) * WS_STRIDE;

  float M = -1e30f;
  for (int s = 0; s < nb; ++s) M = fmaxf(M, base[s * WS_STRIDE + g]);
  float Lsum = 0.f, A = 0.f;
  for (int s = 0; s < nb; ++s) {
    float e = __expf(base[s * WS_STRIDE + g] - M);
    Lsum += base[s * WS_STRIDE + GQ + g] * e;
    A    += base[s * WS_STRIDE + 8 + g * HD + d] * e;
  }
  out[((size_t)(b * NUM_HEADS) + kv * GQ + g) * HD + d] = A / Lsum;
}

extern "C" void kernel_launch(void* const* d_in, const int* in_sizes, int n_in,
                              void* d_out, int out_size, void* d_ws, size_t ws_size,
                              hipStream_t stream) {
  const float* q  = (const float*)d_in[0];
  const float* k  = (const float*)d_in[1];
  const float* v  = (const float*)d_in[2];
  const float* kc = (const float*)d_in[3];
  const float* vc = (const float*)d_in[4];
  const int* block_tables = (const int*)d_in[5];
  const int* context_lens = (const int*)d_in[6];
  // d_in[7] = slot_mapping: not needed (new-token position derived from context_lens)

  float* ws = (float*)d_ws;
  float* out = (float*)d_out;

  size_t need32 = (size_t)NGROUP * 32 * WS_STRIDE * sizeof(float);
  if (ws_size >= need32) {
    // balanced partition: ~768 equal pieces (~3 per CU), up to 32 pieces/group
    pa_partial<32, 768, 64><<<GRID, 256, 0, stream>>>(
        q, k, v, kc, vc, block_tables, context_lens, ws);
    pa_reduce<32, 768, 64><<<BATCH * NUM_KV * GQ, 128, 0, stream>>>(ws, context_lens, out);
  } else {
    // fallback: fixed 256-token pieces (P clamps to 256), 8 slots/group
    pa_partial<8, 512, 256><<<GRID, 256, 0, stream>>>(
        q, k, v, kc, vc, block_tables, context_lens, ws);
    pa_reduce<8, 512, 256><<<BATCH * NUM_KV * GQ, 128, 0, stream>>>(ws, context_lens, out);
  }
}